// Round 1
// baseline (189.340 us; speedup 1.0000x reference)
//
#include <hip/hip_runtime.h>

#define BT_ROWS 65536      // 8*8192 rows
#define DIM     512
#define NK      32
#define TPB     256
#define NBLK    (BT_ROWS / TPB)   // 256 blocks

// d_ws layout: float c2[NK] | float blockloss[NBLK] | int counts[NK]

__global__ void vq_prep(const float* __restrict__ cb, float* __restrict__ c2,
                        int* __restrict__ counts) {
    int t = threadIdx.x;
    if (t < NK) {
        const float4* c4 = (const float4*)(cb + t * DIM);
        float s = 0.f;
#pragma unroll 8
        for (int i = 0; i < DIM / 4; ++i) {
            float4 v = c4[i];
            s += v.x * v.x + v.y * v.y + v.z * v.z + v.w * v.w;
        }
        c2[t] = s;
    } else if (t < 2 * NK) {
        counts[t - NK] = 0;
    }
}

__global__ __launch_bounds__(TPB) void vq_main(const float* __restrict__ x,
                                               const float* __restrict__ cb,
                                               const float* __restrict__ c2,
                                               float* __restrict__ out,
                                               float* __restrict__ blockloss,
                                               int* __restrict__ counts) {
    const int tid  = threadIdx.x;
    const int row  = blockIdx.x * TPB + tid;
    const int lane = tid & 63;
    const int wv   = tid >> 6;

    float acc[NK];
#pragma unroll
    for (int k = 0; k < NK; ++k) acc[k] = 0.f;
    float x2 = 0.f;

    const float4* __restrict__ xr  = (const float4*)(x + (size_t)row * DIM);
    const float4* __restrict__ cb4 = (const float4*)cb;

    // 16 super-chunks of 32 floats, double-buffered x prefetch
    float4 xv[8], xn[8];
#pragma unroll
    for (int j = 0; j < 8; ++j) xv[j] = xr[j];

#pragma unroll 2
    for (int c = 0; c < DIM / 32; ++c) {
        const int cn = (c + 1) & 15;   // last iter harmlessly reloads chunk 0 (L1-hot)
#pragma unroll
        for (int j = 0; j < 8; ++j) xn[j] = xr[cn * 8 + j];

#pragma unroll
        for (int j = 0; j < 8; ++j)
            x2 += xv[j].x * xv[j].x + xv[j].y * xv[j].y + xv[j].z * xv[j].z + xv[j].w * xv[j].w;

#pragma unroll
        for (int k = 0; k < NK; ++k) {
            // uniform address across the wave -> scalar-cache / single L1 request
            const float4* cp = cb4 + k * (DIM / 4) + c * 8;
            float s0 = 0.f, s1 = 0.f, s2 = 0.f, s3 = 0.f;
#pragma unroll
            for (int j = 0; j < 8; ++j) {
                float4 cv = cp[j];
                s0 += xv[j].x * cv.x;
                s1 += xv[j].y * cv.y;
                s2 += xv[j].z * cv.z;
                s3 += xv[j].w * cv.w;
            }
            acc[k] += (s0 + s1) + (s2 + s3);
        }
#pragma unroll
        for (int j = 0; j < 8; ++j) xv[j] = xn[j];
    }

    // dist_k = (x2 + c2[k]) - 2*acc[k]  -- same expansion/rounding shape as the reference.
    // keep-first on ties (ascending k) to mimic np.argmin.
    int   kmin = 0;
    float best = x2 + c2[0] - 2.f * acc[0];
#pragma unroll
    for (int k = 1; k < NK; ++k) {
        float d = x2 + c2[k] - 2.f * acc[k];
        if (d < best) { best = d; kmin = k; }
    }

    // best == sum_d (q - x)^2 for this row (expansion form); reduce for the loss
    float ls = best;
#pragma unroll
    for (int m = 32; m; m >>= 1) ls += __shfl_xor(ls, m, 64);

    __shared__ float         wls[TPB / 64];
    __shared__ int           hist[NK];
    __shared__ unsigned char karr[TPB];

    if (tid < NK) hist[tid] = 0;
    karr[tid] = (unsigned char)kmin;
    if (lane == 0) wls[wv] = ls;
    __syncthreads();

    atomicAdd(&hist[kmin], 1);
    if (tid == 0) blockloss[blockIdx.x] = wls[0] + wls[1] + wls[2] + wls[3];
    __syncthreads();

    if (tid < NK) {
        int h = hist[tid];
        if (h) atomicAdd(&counts[tid], h);
    }

    // cooperative coalesced q-write: each wave writes its own 64 rows, 1KB per store pass
    float4* __restrict__ o4 = (float4*)out;
    const size_t wrow0 = (size_t)blockIdx.x * TPB + (size_t)(wv << 6);
#pragma unroll 1
    for (int r = 0; r < 64; ++r) {
        int    kr   = karr[(wv << 6) + r];          // LDS broadcast, uniform per wave
        size_t base = (wrow0 + (size_t)r) * (DIM / 4);
        o4[base + lane]      = cb4[kr * (DIM / 4) + lane];
        o4[base + 64 + lane] = cb4[kr * (DIM / 4) + 64 + lane];
    }
}

__global__ void vq_final(const float* __restrict__ blockloss, const int* __restrict__ counts,
                         float* __restrict__ out) {
    int   t = threadIdx.x;      // 256 threads
    float v = blockloss[t];
#pragma unroll
    for (int m = 32; m; m >>= 1) v += __shfl_xor(v, m, 64);
    __shared__ float red[4];
    if ((t & 63) == 0) red[t >> 6] = v;
    __syncthreads();
    if (t == 0)
        out[(size_t)BT_ROWS * DIM] =
            1.25f * (red[0] + red[1] + red[2] + red[3]) / (float)((size_t)BT_ROWS * DIM);
    if (t < NK)
        out[(size_t)BT_ROWS * DIM + 1 + t] = (float)counts[t];
}

extern "C" void kernel_launch(void* const* d_in, const int* in_sizes, int n_in,
                              void* d_out, int out_size, void* d_ws, size_t ws_size,
                              hipStream_t stream) {
    const float* x  = (const float*)d_in[0];
    const float* cb = (const float*)d_in[1];
    float* out = (float*)d_out;

    float* c2        = (float*)d_ws;
    float* blockloss = c2 + NK;
    int*   counts    = (int*)(blockloss + NBLK);

    vq_prep<<<1, 64, 0, stream>>>(cb, c2, counts);
    vq_main<<<NBLK, TPB, 0, stream>>>(x, cb, c2, out, blockloss, counts);
    vq_final<<<1, 256, 0, stream>>>(blockloss, counts, out);
}